// Round 15
// baseline (1550.863 us; speedup 1.0000x reference)
//
#include <hip/hip_runtime.h>
#include <hip/hip_bf16.h>

typedef __attribute__((ext_vector_type(8))) short bf16x8;
typedef __attribute__((ext_vector_type(4))) short bf16x4;
typedef __attribute__((ext_vector_type(4))) float f32x4;

#define LB __launch_bounds__(256)

__device__ __forceinline__ unsigned short f2b(float f) {
  __hip_bfloat16 h = __float2bfloat16(f);
  return __builtin_bit_cast(unsigned short, h);
}

// async global->LDS, 16B per lane. LDS dest must be wave-uniform base + lane*16.
#define GLDS(gp, lp)                                                        \
  __builtin_amdgcn_global_load_lds(                                         \
      (const __attribute__((address_space(1))) void*)(gp),                  \
      (__attribute__((address_space(3))) void*)(lp), 16, 0, 0)

// counted vmcnt wait + fence; barrier with trailing fence (pin ds_read/GLDS order)
#define WAITV(n) asm volatile("s_waitcnt vmcnt(" #n ")" ::: "memory")
#define SBAR() do { __builtin_amdgcn_s_barrier(); asm volatile("" ::: "memory"); } while (0)

// ---------------- embed ----------------
__global__ LB void embed_kernel(const int* __restrict__ idx, const float* __restrict__ tok,
                                const float* __restrict__ pos, float* __restrict__ X) {
  const int m = blockIdx.x;
  const int t = m & 1023;
  const int token = idx[m];
  const int c = threadIdx.x * 4;
  const float4 a = *(const float4*)(tok + (size_t)token * 1024 + c);
  const float4 p = *(const float4*)(pos + (size_t)t * 1024 + c);
  float4 o; o.x = a.x + p.x; o.y = a.y + p.y; o.z = a.z + p.z; o.w = a.w + p.w;
  *(float4*)(X + (size_t)m * 1024 + c) = o;
}

// ---------------- layernorm ----------------
template<bool WF32>
__global__ LB void ln_kernel(const float* __restrict__ X, const float* __restrict__ W,
                             float* __restrict__ Yf, unsigned short* __restrict__ Yb) {
  const int row = blockIdx.x;
  const float* xr = X + (size_t)row * 1024;
  const int c = threadIdx.x * 4;
  const float4 v = *(const float4*)(xr + c);
  float s = v.x + v.y + v.z + v.w;
  float q = v.x*v.x + v.y*v.y + v.z*v.z + v.w*v.w;
  #pragma unroll
  for (int d = 32; d > 0; d >>= 1) { s += __shfl_down(s, d); q += __shfl_down(q, d); }
  __shared__ float ss[4], sq[4];
  const int wid = threadIdx.x >> 6;
  if ((threadIdx.x & 63) == 0) { ss[wid] = s; sq[wid] = q; }
  __syncthreads();
  const float fs = ss[0] + ss[1] + ss[2] + ss[3];
  const float fq = sq[0] + sq[1] + sq[2] + sq[3];
  const float mean = fs * (1.0f / 1024.0f);
  const float var = fq * (1.0f / 1024.0f) - mean * mean;
  const float rstd = rsqrtf(var + 1e-5f);
  const float4 w = *(const float4*)(W + c);
  float4 o;
  o.x = (v.x - mean) * rstd * w.x; o.y = (v.y - mean) * rstd * w.y;
  o.z = (v.z - mean) * rstd * w.z; o.w = (v.w - mean) * rstd * w.w;
  if (WF32) *(float4*)(Yf + (size_t)row * 1024 + c) = o;
  unsigned long long pk = (unsigned long long)f2b(o.x)
      | ((unsigned long long)f2b(o.y) << 16)
      | ((unsigned long long)f2b(o.z) << 32)
      | ((unsigned long long)f2b(o.w) << 48);
  *(unsigned long long*)(Yb + (size_t)row * 1024 + c) = pk;
}

// ---------------- transpose tile body ----------------
__device__ __forceinline__ void tr_body(const float* __restrict__ src,
                                        unsigned short* __restrict__ dst,
                                        int C, int rowOff, int ldDst, int bx, int by) {
  __shared__ float tile[32][33];
  const int c0 = bx * 32, r0 = by * 32;
  const int tx = threadIdx.x & 31, ty = threadIdx.x >> 5;
  #pragma unroll
  for (int u = 0; u < 4; ++u)
    tile[ty + u * 8][tx] = src[(size_t)(r0 + ty + u * 8) * C + c0 + tx];
  __syncthreads();
  const int ci = threadIdx.x >> 4;
  const int rp = threadIdx.x & 15;
  #pragma unroll
  for (int u = 0; u < 2; ++u) {
    const int c = ci + u * 16;
    unsigned int pk = (unsigned int)f2b(tile[rp * 2][c])
                    | ((unsigned int)f2b(tile[rp * 2 + 1][c]) << 16);
    *(unsigned int*)&dst[(size_t)(rowOff + c0 + c) * ldDst + r0 + rp * 2] = pk;
  }
}

// lm_head transpose (standalone)
__global__ LB void transpose_w(const float* __restrict__ src, unsigned short* __restrict__ dst,
                               int C, int rowOff, int ldDst) {
  tr_body(src, dst, C, rowOff, ldDst, blockIdx.x, blockIdx.y);
}

// all per-layer weight transposes in ONE launch: 10752 flat blocks
__global__ LB void transpose_all(const float* __restrict__ qp, const float* __restrict__ op,
                                 const float* __restrict__ kvp, unsigned short* __restrict__ dstQ,
                                 const float* __restrict__ f1, const float* __restrict__ f2,
                                 unsigned short* __restrict__ F1T, unsigned short* __restrict__ F2T) {
  int id = blockIdx.x;
  if (id < 2560) {
    const float* src; int C, rowOff, bx, by;
    if (id < 2048) {
      src = (id < 1024) ? qp : op;
      rowOff = (id < 1024) ? 0 : 1536;
      id &= 1023; C = 1024; bx = id & 31; by = id >> 5;
    } else {
      id -= 2048;
      src = (id < 256) ? kvp : (kvp + 1024 * 256);
      rowOff = (id < 256) ? 1024 : 1280;
      id &= 255; C = 256; bx = id & 7; by = id >> 3;
    }
    tr_body(src, dstQ, C, rowOff, 1024, bx, by);
  } else {
    id -= 2560;
    if (id < 4096) {
      tr_body(f1, F1T, 4096, 0, 1024, id & 127, id >> 7);
    } else {
      id -= 4096;
      tr_body(f2, F2T, 1024, 0, 4096, id & 31, id >> 5);
    }
  }
}

// ---------------- fused flash attention: dbuf K/V, 64-row q-tiles, 2 blocks/CU ----------------
__global__ LB void attn_fused(const unsigned short* __restrict__ qkvb,
                              const unsigned short* __restrict__ vT,
                              unsigned short* __restrict__ ob) {
  const int qt = 15 - blockIdx.x, bh = blockIdx.y;
  const int b = bh >> 4, hh = bh & 15, n = hh & 3;
  const int tid = threadIdx.x, lane = tid & 63, w = tid >> 6;
  const int g = lane >> 4, c = lane & 15;
  const int q0w = qt * 64 + w * 16;
  const int qrow = q0w + c;

  __shared__ unsigned short lsK[2][64 * 64];
  __shared__ unsigned short lsV[2][64 * 64];
  __shared__ unsigned short lsP[4][16 * 64];
  unsigned short* Pw = lsP[w];

  bf16x8 qf[2];
  {
    const unsigned short* Qb = qkvb + (size_t)(b * 1024 + q0w) * 1536 + hh * 64;
    #pragma unroll
    for (int ks = 0; ks < 2; ++ks)
      qf[ks] = *(const bf16x8*)(Qb + (size_t)c * 1536 + ks * 32 + g * 8);
  }

  f32x4 accO[4] = {};
  float mr = -1e30f, lr = 0.0f;

  const int srow = tid >> 3;
  const int scol = ((tid & 7) ^ (srow & 7)) << 3;
  const unsigned short* gK = qkvb + (size_t)(b * 1024 + srow) * 1536 + 1024 + n * 64 + scol;
  const unsigned short* gV = vT + (size_t)((b * 4 + n) * 64 + srow) * 1024 + scol;

  GLDS(gK, &lsK[0][tid * 8]);
  GLDS(gK + (size_t)32 * 1536, &lsK[0][tid * 8 + 2048]);
  GLDS(gV, &lsV[0][tid * 8]);
  GLDS(gV + (size_t)32 * 1024, &lsV[0][tid * 8 + 2048]);
  __syncthreads();

  for (int kt = 0; kt <= qt; ++kt) {
    const int cur = kt & 1;
    if (kt < qt) {
      const size_t ko = (size_t)(kt + 1) * 64;
      GLDS(gK + ko * 1536, &lsK[cur ^ 1][tid * 8]);
      GLDS(gK + (ko + 32) * 1536, &lsK[cur ^ 1][tid * 8 + 2048]);
      GLDS(gV + ko, &lsV[cur ^ 1][tid * 8]);
      GLDS(gV + ko + (size_t)32 * 1024, &lsV[cur ^ 1][tid * 8 + 2048]);
    }
    const unsigned short* K_ = lsK[cur];
    const unsigned short* V_ = lsV[cur];
    const bool dg = (kt == qt);
    const int kb = kt * 64;

    f32x4 st[4] = {};
    #pragma unroll
    for (int ks = 0; ks < 2; ++ks) {
      const int col = (((ks * 4 + g) ^ (lane & 7)) << 3);
      bf16x8 kf[4];
      #pragma unroll
      for (int mi = 0; mi < 4; ++mi)
        kf[mi] = *(const bf16x8*)&K_[(mi * 16 + c) * 64 + col];
      #pragma unroll
      for (int mi = 0; mi < 4; ++mi)
        st[mi] = __builtin_amdgcn_mfma_f32_16x16x32_bf16(kf[mi], qf[ks], st[mi], 0, 0, 0);
    }

    float mx = mr;
    #pragma unroll
    for (int mi = 0; mi < 4; ++mi)
      #pragma unroll
      for (int j = 0; j < 4; ++j) {
        float v = st[mi][j] * 0.125f;
        if (dg && (kb + mi * 16 + g * 4 + j) > qrow) v = -1e30f;
        st[mi][j] = v;
        mx = fmaxf(mx, v);
      }
    mx = fmaxf(mx, __shfl_xor(mx, 16));
    mx = fmaxf(mx, __shfl_xor(mx, 32));
    const float al = __expf(mr - mx);
    float sum = 0.0f;
    #pragma unroll
    for (int mi = 0; mi < 4; ++mi) {
      bf16x4 pk;
      #pragma unroll
      for (int j = 0; j < 4; ++j) {
        const float e = __expf(st[mi][j] - mx);
        sum += e;
        pk[j] = (short)f2b(e);
      }
      *(bf16x4*)&Pw[c * 64 + ((mi * 16 + g * 4) ^ ((c & 7) << 3))] = pk;
    }
    sum += __shfl_xor(sum, 16);
    sum += __shfl_xor(sum, 32);
    lr = lr * al + sum;
    mr = mx;

    float aj[4];
    #pragma unroll
    for (int j = 0; j < 4; ++j) aj[j] = __shfl(al, g * 4 + j);
    #pragma unroll
    for (int dj = 0; dj < 4; ++dj)
      #pragma unroll
      for (int j = 0; j < 4; ++j) accO[dj][j] *= aj[j];

    #pragma unroll
    for (int ks = 0; ks < 2; ++ks) {
      const int col = (((ks * 4 + g) ^ (c & 7)) << 3);
      const bf16x8 pa = *(const bf16x8*)&Pw[c * 64 + col];
      bf16x8 vf[4];
      #pragma unroll
      for (int dj = 0; dj < 4; ++dj)
        vf[dj] = *(const bf16x8*)&V_[(dj * 16 + c) * 64 + col];
      #pragma unroll
      for (int dj = 0; dj < 4; ++dj)
        accO[dj] = __builtin_amdgcn_mfma_f32_16x16x32_bf16(pa, vf[dj], accO[dj], 0, 0, 0);
    }
    __syncthreads();
  }

  const float linv = 1.0f / lr;
  float lj[4];
  #pragma unroll
  for (int j = 0; j < 4; ++j) lj[j] = __shfl(linv, g * 4 + j);
  unsigned short* obase = ob + (size_t)(b * 1024 + q0w) * 1024 + hh * 64;
  #pragma unroll
  for (int dj = 0; dj < 4; ++dj)
    #pragma unroll
    for (int j = 0; j < 4; ++j)
      obase[(size_t)(g * 4 + j) * 1024 + dj * 16 + c] = f2b(accO[dj][j] * lj[j]);
}

// ---------------- NT GEMM: C = A[M,K]*Bt[N,K]^T, bf16 in, f32 acc ----------------
template<int BM, int BN, bool BF16OUT, bool RELU, bool RESID, bool WVT = false, bool DBUF = false>
__global__ LB void gemm_nt(const unsigned short* __restrict__ A, const unsigned short* __restrict__ Bt,
                           void* __restrict__ Cv, const float* __restrict__ Res,
                           unsigned short* __restrict__ vTo,
                           int K, int lda, int ldb, int ldc) {
  constexpr int BK = 64;
  constexpr int WM = BM / 2, WN = BN / 2;
  constexpr int FM = WM / 16, FN = WN / 16;
  constexpr int PA = BM / 32, PB = BN / 32;
  constexpr int NB = DBUF ? 2 : 1;
  int f = blockIdx.x + gridDim.x * blockIdx.y;
  const int nwg = gridDim.x * gridDim.y;
  if ((nwg & 7) == 0) f = (f & 7) * (nwg >> 3) + (f >> 3);
  const int bx = f % gridDim.x, by = f / gridDim.x;

  const int tid = threadIdx.x;
  const int lane = tid & 63, wid = tid >> 6;
  const int wr = wid >> 1, wc = wid & 1;
  const int m0 = bx * BM, n0 = by * BN;

  __shared__ unsigned short lsA[NB][BM * BK];
  __shared__ unsigned short lsB[NB][BN * BK];

  f32x4 acc[FM][FN] = {};

  const int srow = tid >> 3;
  const int scol = ((tid & 7) ^ (srow & 7)) << 3;
  const unsigned short* gA = A + (size_t)(m0 + srow) * lda + scol;
  const unsigned short* gB = Bt + (size_t)(n0 + srow) * ldb + scol;

  const int fr = lane & 15;
  const int j7 = lane & 7;
  const int g4 = lane >> 4;

  if (DBUF) {
    #pragma unroll
    for (int p = 0; p < PA; ++p) GLDS(gA + (size_t)(p * 32) * lda, &lsA[0][tid * 8 + p * 2048]);
    #pragma unroll
    for (int p = 0; p < PB; ++p) GLDS(gB + (size_t)(p * 32) * ldb, &lsB[0][tid * 8 + p * 2048]);
    __syncthreads();
  }

  for (int k0 = 0; k0 < K; k0 += BK) {
    int cur = 0;
    if (DBUF) {
      cur = (k0 >> 6) & 1;
      if (k0 + BK < K) {
        #pragma unroll
        for (int p = 0; p < PA; ++p)
          GLDS(gA + (size_t)(p * 32) * lda + k0 + BK, &lsA[cur ^ 1][tid * 8 + p * 2048]);
        #pragma unroll
        for (int p = 0; p < PB; ++p)
          GLDS(gB + (size_t)(p * 32) * ldb + k0 + BK, &lsB[cur ^ 1][tid * 8 + p * 2048]);
      }
    } else {
      if (k0) __syncthreads();
      #pragma unroll
      for (int p = 0; p < PA; ++p)
        GLDS(gA + (size_t)(p * 32) * lda + k0, &lsA[0][tid * 8 + p * 2048]);
      #pragma unroll
      for (int p = 0; p < PB; ++p)
        GLDS(gB + (size_t)(p * 32) * ldb + k0, &lsB[0][tid * 8 + p * 2048]);
      __syncthreads();
    }

    const unsigned short* LA = lsA[cur];
    const unsigned short* LBp = lsB[cur];
    #pragma unroll
    for (int ks = 0; ks < 2; ++ks) {
      const int col = (((ks * 4 + g4) ^ j7) << 3);
      bf16x8 af[FM], bfv[FN];
      #pragma unroll
      for (int mi = 0; mi < FM; ++mi)
        af[mi] = *(const bf16x8*)&LA[(wr * WM + mi * 16 + fr) * BK + col];
      #pragma unroll
      for (int nj = 0; nj < FN; ++nj)
        bfv[nj] = *(const bf16x8*)&LBp[(wc * WN + nj * 16 + fr) * BK + col];
      #pragma unroll
      for (int mi = 0; mi < FM; ++mi)
        #pragma unroll
        for (int nj = 0; nj < FN; ++nj)
          acc[mi][nj] = __builtin_amdgcn_mfma_f32_16x16x32_bf16(af[mi], bfv[nj], acc[mi][nj], 0, 0, 0);
    }
    if (DBUF) __syncthreads();
  }

  const int r0 = (lane >> 4) * 4, c0 = lane & 15;
  #pragma unroll
  for (int mi = 0; mi < FM; ++mi) {
    #pragma unroll
    for (int nj = 0; nj < FN; ++nj) {
      const int c = n0 + wc * WN + nj * 16 + c0;
      const int rb = m0 + wr * WM + mi * 16 + r0;
      unsigned short us[4];
      #pragma unroll
      for (int j = 0; j < 4; ++j) {
        const int r = rb + j;
        float v = acc[mi][nj][j];
        if (RELU) v = fmaxf(v, 0.0f);
        if (RESID) v += Res[(size_t)r * ldc + c];
        const size_t o = (size_t)r * ldc + c;
        if (BF16OUT) { us[j] = f2b(v); ((unsigned short*)Cv)[o] = us[j]; }
        else ((float*)Cv)[o] = v;
      }
      if (WVT && c >= 1280) {
        const int bb = rb >> 10, t0 = rb & 1023;
        bf16x4 pk;
        #pragma unroll
        for (int j = 0; j < 4; ++j) pk[j] = (short)us[j];
        *(bf16x4*)&vTo[((size_t)(bb * 256 + (c - 1280))) * 1024 + t0] = pk;
      }
    }
  }
}

// ---------------- 256x256 8-wave logits GEMM with COUNTED vmcnt pipeline ----------------
// Issue order per tile: B0,B1,B2,B3,A0,A2,A1,A3 (pass p = 64 rows). Phases
// (qm,qn) = (0,0),(0,1),(1,0),(1,1). Waits: vmcnt(2) at tile start (B*,A0,A2
// visible; A1,A3 of current tile stay in flight), vmcnt(4) mid-tile (A1,A3
// visible; next tile's 4 B-prefetches stay in flight); vmcnt(0) mid-tile on the
// last tile. No load is ever force-drained early; >=2 phases of latency cover.
__global__ __launch_bounds__(512) void gemm_big(const unsigned short* __restrict__ A,
                                                const unsigned short* __restrict__ Bt,
                                                float* __restrict__ C,
                                                int K, int lda, int ldb, int ldc) {
  int f = blockIdx.x + gridDim.x * blockIdx.y;
  const int nwg = gridDim.x * gridDim.y;          // must be % 8 == 0
  f = (f & 7) * (nwg >> 3) + (f >> 3);
  const int bx = f % gridDim.x, by = f / gridDim.x;
  const int m0 = bx * 256, n0 = by * 256;

  const int tid = threadIdx.x;
  const int lane = tid & 63, wid = tid >> 6;
  const int wr = wid >> 2, wc = wid & 3;          // 2 x 4 wave grid
  const int fr = lane & 15, g4 = lane >> 4, j7 = lane & 7;

  __shared__ unsigned short lsA[2][256 * 64];
  __shared__ unsigned short lsB[2][256 * 64];     // 128 KiB

  f32x4 acc[8][4] = {};

  const int srow = tid >> 3;                      // 64 rows per staging pass
  const int scol = ((tid & 7) ^ (srow & 7)) << 3;
  const unsigned short* gA = A + (size_t)(m0 + srow) * lda + scol;
  const unsigned short* gB = Bt + (size_t)(n0 + srow) * ldb + scol;

  const int nt = K >> 6;

  // prologue: tile 0 into buffer 0, canonical order B0,B1,B2,B3,A0,A2,A1,A3
  GLDS(gB + (size_t)(0 * 64) * ldb, &lsB[0][tid * 8 + 0 * 4096]);
  GLDS(gB + (size_t)(1 * 64) * ldb, &lsB[0][tid * 8 + 1 * 4096]);
  GLDS(gB + (size_t)(2 * 64) * ldb, &lsB[0][tid * 8 + 2 * 4096]);
  GLDS(gB + (size_t)(3 * 64) * ldb, &lsB[0][tid * 8 + 3 * 4096]);
  GLDS(gA + (size_t)(0 * 64) * lda, &lsA[0][tid * 8 + 0 * 4096]);
  GLDS(gA + (size_t)(2 * 64) * lda, &lsA[0][tid * 8 + 2 * 4096]);
  GLDS(gA + (size_t)(1 * 64) * lda, &lsA[0][tid * 8 + 1 * 4096]);
  GLDS(gA + (size_t)(3 * 64) * lda, &lsA[0][tid * 8 + 3 * 4096]);

  for (int t = 0; t < nt; ++t) {
    const int cur = t & 1;
    const bool pref = (t + 1) < nt;
    const int k1 = (t + 1) << 6;
    const unsigned short* TA = lsA[cur];
    const unsigned short* TB = lsB[cur];
    unsigned short* nA = &lsA[cur ^ 1][tid * 8];
    unsigned short* nB = &lsB[cur ^ 1][tid * 8];

    WAITV(2);        // B0-3, A0, A2 of tile t retired (all waves, same queue)
    SBAR();

    #pragma unroll
    for (int q = 0; q < 4; ++q) {
      const int qm = q >> 1, qn = q & 1;          // phase order (0,0),(0,1),(1,0),(1,1)
      bf16x8 af[2][4], bf[2][2];
      #pragma unroll
      for (int ks = 0; ks < 2; ++ks) {
        const int col = (((ks * 4 + g4) ^ j7) << 3);
        #pragma unroll
        for (int mi = 0; mi < 4; ++mi)
          af[ks][mi] = *(const bf16x8*)&TA[(wr * 128 + qm * 64 + mi * 16 + fr) * 64 + col];
        #pragma unroll
        for (int nj = 0; nj < 2; ++nj)
          bf[ks][nj] = *(const bf16x8*)&TB[(wc * 64 + (qn * 2 + nj) * 16 + fr) * 64 + col];
      }
      if (pref) {   // canonical issue order: q0:B0,B1  q1:B2,B3  q2:A0,A2  q3:A1,A3
        if (q == 0) { GLDS(gB + (size_t)(0 * 64) * ldb + k1, nB + 0 * 4096);
                      GLDS(gB + (size_t)(1 * 64) * ldb + k1, nB + 1 * 4096); }
        else if (q == 1) { GLDS(gB + (size_t)(2 * 64) * ldb + k1, nB + 2 * 4096);
                           GLDS(gB + (size_t)(3 * 64) * ldb + k1, nB + 3 * 4096); }
        else if (q == 2) { GLDS(gA + (size_t)(0 * 64) * lda + k1, nA + 0 * 4096);
                           GLDS(gA + (size_t)(2 * 64) * lda + k1, nA + 2 * 4096); }
        else { GLDS(gA + (size_t)(1 * 64) * lda + k1, nA + 1 * 4096);
               GLDS(gA + (size_t)(3 * 64) * lda + k1, nA + 3 * 4096); }
      }
      SBAR();
      __builtin_amdgcn_s_setprio(1);
      #pragma unroll
      for (int ks = 0; ks < 2; ++ks)
        #pragma unroll
        for (int mi = 0; mi < 4; ++mi)
          #pragma unroll
          for (int nj = 0; nj < 2; ++nj)
            acc[qm * 4 + mi][qn * 2 + nj] = __builtin_amdgcn_mfma_f32_16x16x32_bf16(
                af[ks][mi], bf[ks][nj], acc[qm * 4 + mi][qn * 2 + nj], 0, 0, 0);
      __builtin_amdgcn_s_setprio(0);
      SBAR();
      if (q == 1) {              // mid-tile: A1,A3 of tile t must land before qm=1 phases
        if (pref) WAITV(4);      // leaves next tile's B0-3 in flight
        else      WAITV(0);
        SBAR();
      }
    }
  }

  // epilogue: C/D layout col=lane&15, row=(lane>>4)*4+reg  (acc[mi] rows = mi*16)
  #pragma unroll
  for (int mi = 0; mi < 8; ++mi) {
    #pragma unroll
    for (int nj = 0; nj < 4; ++nj) {
      const int cc = n0 + wc * 64 + nj * 16 + fr;
      #pragma unroll
      for (int j = 0; j < 4; ++j) {
        const int rr = m0 + wr * 128 + mi * 16 + g4 * 4 + j;
        C[(size_t)rr * ldc + cc] = acc[mi][nj][j];
      }
    }
  }
}

extern "C" void kernel_launch(void* const* d_in, const int* in_sizes, int n_in,
                              void* d_out, int out_size, void* d_ws, size_t ws_size,
                              hipStream_t stream) {
  (void)in_sizes; (void)n_in; (void)out_size;
  const int*   idx      = (const int*)d_in[0];
  const float* tok_emb  = (const float*)d_in[1];
  const float* pos_emb  = (const float*)d_in[2];
  const float* q_proj   = (const float*)d_in[3];
  const float* kv_proj  = (const float*)d_in[4];
  const float* out_proj = (const float*)d_in[5];
  const float* fc_in    = (const float*)d_in[6];
  const float* fc_out   = (const float*)d_in[7];
  const float* scale    = (const float*)d_in[8];
  const float* out_scl  = (const float*)d_in[9];
  const float* lm_head  = (const float*)d_in[10];
  float* out = (float*)d_out;

  char* ws = (char*)d_ws;
  size_t off = 0;
  auto alloc = [&](size_t bytes) -> void* {
    void* p = ws + off;
    off += (bytes + 255) & ~(size_t)255;
    return p;
  };
  unsigned short* WqkvT = (unsigned short*)alloc((size_t)2560 * 1024 * 2);
  unsigned short* WoT   = WqkvT + (size_t)1536 * 1024;
  unsigned short* F1T   = (unsigned short*)alloc((size_t)4096 * 1024 * 2);
  unsigned short* F2T   = (unsigned short*)alloc((size_t)1024 * 4096 * 2);
  float*  xbuf  = (float*)alloc((size_t)2048 * 1024 * 4);
  float*  hbuf  = (float*)alloc((size_t)2048 * 1024 * 4);
  float*  h2buf = (float*)alloc((size_t)2048 * 1024 * 4);
  unsigned short* actb  = (unsigned short*)alloc((size_t)2048 * 1024 * 2);
  unsigned short* qkvb  = (unsigned short*)alloc((size_t)2048 * 1536 * 2);
  unsigned short* vT    = (unsigned short*)alloc((size_t)2 * 256 * 1024 * 2);
  unsigned short* LmT   = (unsigned short*)alloc((size_t)32000 * 1024 * 2);
  unsigned short* ob    = (unsigned short*)alloc((size_t)2048 * 1024 * 2);
  unsigned short* m1    = (unsigned short*)alloc((size_t)2048 * 4096 * 2);
  if (off > ws_size) return;

  const dim3 thr(256);

  embed_kernel<<<dim3(2048), thr, 0, stream>>>(idx, tok_emb, pos_emb, xbuf);

  for (int l = 0; l < 8; ++l) {
    const float* qp  = q_proj + (size_t)l * 1024 * 1024;
    const float* op  = out_proj + (size_t)l * 1024 * 1024;
    const float* kvp = kv_proj + (size_t)l * 2 * 1024 * 256;
    transpose_all<<<dim3(10752), thr, 0, stream>>>(
        qp, op, kvp, WqkvT,
        fc_in + (size_t)l * 1024 * 4096, fc_out + (size_t)l * 4096 * 1024, F1T, F2T);

    const float* w1 = scale + (size_t)l * 2048;
    const float* w2 = w1 + 1024;

    ln_kernel<true><<<dim3(2048), thr, 0, stream>>>(xbuf, w1, hbuf, actb);
    gemm_nt<128, 64, true, false, false, true, true><<<dim3(16, 24), thr, 0, stream>>>(
        actb, WqkvT, qkvb, nullptr, vT, 1024, 1024, 1024, 1536);
    attn_fused<<<dim3(16, 32), thr, 0, stream>>>(qkvb, vT, ob);
    gemm_nt<128, 64, false, false, true, false, true><<<dim3(16, 16), thr, 0, stream>>>(
        ob, WoT, xbuf, hbuf, nullptr, 1024, 1024, 1024, 1024);
    ln_kernel<true><<<dim3(2048), thr, 0, stream>>>(xbuf, w2, h2buf, actb);
    gemm_nt<128, 128, true, true, false, false, true><<<dim3(16, 32), thr, 0, stream>>>(
        actb, F1T, m1, nullptr, nullptr, 1024, 1024, 1024, 4096);
    gemm_nt<128, 64, false, false, true, false, true><<<dim3(16, 16), thr, 0, stream>>>(
        m1, F2T, xbuf, h2buf, nullptr, 4096, 4096, 4096, 1024);
  }

  transpose_w<<<dim3(1000, 32), thr, 0, stream>>>(lm_head, LmT, 32000, 0, 1024);
  ln_kernel<false><<<dim3(2048), thr, 0, stream>>>(xbuf, out_scl, nullptr, actb);
  // logits: 256^2 8-wave counted-vmcnt kernel, grid 8x125 = 1000 blocks (%8==0)
  gemm_big<<<dim3(8, 125), dim3(512), 0, stream>>>(actb, LmT, out, 1024, 1024, 1024, 32000);
}

// Round 16
// 1528.306 us; speedup vs baseline: 1.0148x; 1.0148x over previous
//
#include <hip/hip_runtime.h>
#include <hip/hip_bf16.h>

typedef __attribute__((ext_vector_type(8))) short bf16x8;
typedef __attribute__((ext_vector_type(4))) short bf16x4;
typedef __attribute__((ext_vector_type(4))) float f32x4;

#define LB __launch_bounds__(256)

__device__ __forceinline__ unsigned short f2b(float f) {
  __hip_bfloat16 h = __float2bfloat16(f);
  return __builtin_bit_cast(unsigned short, h);
}

// async global->LDS, 16B per lane. LDS dest must be wave-uniform base + lane*16.
#define GLDS(gp, lp)                                                        \
  __builtin_amdgcn_global_load_lds(                                         \
      (const __attribute__((address_space(1))) void*)(gp),                  \
      (__attribute__((address_space(3))) void*)(lp), 16, 0, 0)

// ---------------- embed ----------------
__global__ LB void embed_kernel(const int* __restrict__ idx, const float* __restrict__ tok,
                                const float* __restrict__ pos, float* __restrict__ X) {
  const int m = blockIdx.x;
  const int t = m & 1023;
  const int token = idx[m];
  const int c = threadIdx.x * 4;
  const float4 a = *(const float4*)(tok + (size_t)token * 1024 + c);
  const float4 p = *(const float4*)(pos + (size_t)t * 1024 + c);
  float4 o; o.x = a.x + p.x; o.y = a.y + p.y; o.z = a.z + p.z; o.w = a.w + p.w;
  *(float4*)(X + (size_t)m * 1024 + c) = o;
}

// ---------------- layernorm row body (block-uniform call; safe __syncthreads) ----------------
__device__ __forceinline__ void ln_row(const float* __restrict__ X, const float* __restrict__ W,
                                       float* __restrict__ Yf, unsigned short* __restrict__ Yb,
                                       int row, bool wf32) {
  const int c = threadIdx.x * 4;
  const size_t base = (size_t)row * 1024 + c;
  const float4 v = *(const float4*)(X + base);
  float s = v.x + v.y + v.z + v.w;
  float q = v.x*v.x + v.y*v.y + v.z*v.z + v.w*v.w;
  #pragma unroll
  for (int d = 32; d > 0; d >>= 1) { s += __shfl_down(s, d); q += __shfl_down(q, d); }
  __shared__ float ss[4], sq[4];
  const int wid = threadIdx.x >> 6;
  if ((threadIdx.x & 63) == 0) { ss[wid] = s; sq[wid] = q; }
  __syncthreads();
  const float fs = ss[0] + ss[1] + ss[2] + ss[3];
  const float fq = sq[0] + sq[1] + sq[2] + sq[3];
  const float mean = fs * (1.0f / 1024.0f);
  const float var = fq * (1.0f / 1024.0f) - mean * mean;
  const float rstd = rsqrtf(var + 1e-5f);
  const float4 w = *(const float4*)(W + c);
  float4 o;
  o.x = (v.x - mean) * rstd * w.x; o.y = (v.y - mean) * rstd * w.y;
  o.z = (v.z - mean) * rstd * w.z; o.w = (v.w - mean) * rstd * w.w;
  if (wf32) *(float4*)(Yf + base) = o;
  unsigned long long pk = (unsigned long long)f2b(o.x)
      | ((unsigned long long)f2b(o.y) << 16)
      | ((unsigned long long)f2b(o.z) << 32)
      | ((unsigned long long)f2b(o.w) << 48);
  *(unsigned long long*)(Yb + base) = pk;
}

template<bool WF32>
__global__ LB void ln_kernel(const float* __restrict__ X, const float* __restrict__ W,
                             float* __restrict__ Yf, unsigned short* __restrict__ Yb) {
  ln_row(X, W, Yf, Yb, blockIdx.x, WF32);
}

// ---------------- transpose tile body: dst[rowOff+c][r] = bf16(src[r][c]) ----------------
__device__ __forceinline__ void tr_body(const float* __restrict__ src,
                                        unsigned short* __restrict__ dst,
                                        int C, int rowOff, int ldDst, int bx, int by) {
  __shared__ float tile[32][33];
  const int c0 = bx * 32, r0 = by * 32;
  const int tx = threadIdx.x & 31, ty = threadIdx.x >> 5;
  #pragma unroll
  for (int u = 0; u < 4; ++u)
    tile[ty + u * 8][tx] = src[(size_t)(r0 + ty + u * 8) * C + c0 + tx];
  __syncthreads();
  const int ci = threadIdx.x >> 4;
  const int rp = threadIdx.x & 15;
  #pragma unroll
  for (int u = 0; u < 2; ++u) {
    const int c = ci + u * 16;
    unsigned int pk = (unsigned int)f2b(tile[rp * 2][c])
                    | ((unsigned int)f2b(tile[rp * 2 + 1][c]) << 16);
    *(unsigned int*)&dst[(size_t)(rowOff + c0 + c) * ldDst + r0 + rp * 2] = pk;
  }
}

// merged per-layer: ln1 (blocks 0..2047) + all weight transposes (blocks 2048..14847)
__global__ LB void tr_ln(const float* __restrict__ qp, const float* __restrict__ op,
                         const float* __restrict__ kvp, unsigned short* __restrict__ dstQ,
                         const float* __restrict__ f1, const float* __restrict__ f2,
                         unsigned short* __restrict__ F1T, unsigned short* __restrict__ F2T,
                         const float* __restrict__ X, const float* __restrict__ W,
                         float* __restrict__ Yf, unsigned short* __restrict__ Yb) {
  int id = blockIdx.x;
  if (id < 2048) { ln_row(X, W, Yf, Yb, id, true); return; }
  id -= 2048;
  if (id < 2560) {
    const float* src; int C, rowOff, bx, by;
    if (id < 2048) {
      src = (id < 1024) ? qp : op;
      rowOff = (id < 1024) ? 0 : 1536;
      id &= 1023; C = 1024; bx = id & 31; by = id >> 5;
    } else {
      id -= 2048;
      src = (id < 256) ? kvp : (kvp + 1024 * 256);
      rowOff = (id < 256) ? 1024 : 1280;
      id &= 255; C = 256; bx = id & 7; by = id >> 3;
    }
    tr_body(src, dstQ, C, rowOff, 1024, bx, by);
  } else {
    id -= 2560;
    if (id < 4096) {
      tr_body(f1, F1T, 4096, 0, 1024, id & 127, id >> 7);
    } else {
      id -= 4096;
      tr_body(f2, F2T, 1024, 0, 4096, id & 31, id >> 5);
    }
  }
}

// merged tail: final ln (blocks 0..2047) + lm_head transpose (blocks 2048..34047)
__global__ LB void tr_ln_tail(const float* __restrict__ lm, unsigned short* __restrict__ LmT,
                              const float* __restrict__ X, const float* __restrict__ W,
                              unsigned short* __restrict__ Yb) {
  int id = blockIdx.x;
  if (id < 2048) { ln_row(X, W, nullptr, Yb, id, false); return; }
  id -= 2048;
  const int bx = id % 1000, by = id / 1000;
  tr_body(lm, LmT, 32000, 0, 1024, bx, by);
}

// ---------------- fused flash attention: dbuf K/V, 64-row q-tiles, 2 blocks/CU ----------------
__global__ LB void attn_fused(const unsigned short* __restrict__ qkvb,
                              const unsigned short* __restrict__ vT,
                              unsigned short* __restrict__ ob) {
  const int qt = 15 - blockIdx.x, bh = blockIdx.y;
  const int b = bh >> 4, hh = bh & 15, n = hh & 3;
  const int tid = threadIdx.x, lane = tid & 63, w = tid >> 6;
  const int g = lane >> 4, c = lane & 15;
  const int q0w = qt * 64 + w * 16;
  const int qrow = q0w + c;

  __shared__ unsigned short lsK[2][64 * 64];
  __shared__ unsigned short lsV[2][64 * 64];
  __shared__ unsigned short lsP[4][16 * 64];
  unsigned short* Pw = lsP[w];

  bf16x8 qf[2];
  {
    const unsigned short* Qb = qkvb + (size_t)(b * 1024 + q0w) * 1536 + hh * 64;
    #pragma unroll
    for (int ks = 0; ks < 2; ++ks)
      qf[ks] = *(const bf16x8*)(Qb + (size_t)c * 1536 + ks * 32 + g * 8);
  }

  f32x4 accO[4] = {};
  float mr = -1e30f, lr = 0.0f;

  const int srow = tid >> 3;
  const int scol = ((tid & 7) ^ (srow & 7)) << 3;
  const unsigned short* gK = qkvb + (size_t)(b * 1024 + srow) * 1536 + 1024 + n * 64 + scol;
  const unsigned short* gV = vT + (size_t)((b * 4 + n) * 64 + srow) * 1024 + scol;

  GLDS(gK, &lsK[0][tid * 8]);
  GLDS(gK + (size_t)32 * 1536, &lsK[0][tid * 8 + 2048]);
  GLDS(gV, &lsV[0][tid * 8]);
  GLDS(gV + (size_t)32 * 1024, &lsV[0][tid * 8 + 2048]);
  __syncthreads();

  for (int kt = 0; kt <= qt; ++kt) {
    const int cur = kt & 1;
    if (kt < qt) {
      const size_t ko = (size_t)(kt + 1) * 64;
      GLDS(gK + ko * 1536, &lsK[cur ^ 1][tid * 8]);
      GLDS(gK + (ko + 32) * 1536, &lsK[cur ^ 1][tid * 8 + 2048]);
      GLDS(gV + ko, &lsV[cur ^ 1][tid * 8]);
      GLDS(gV + ko + (size_t)32 * 1024, &lsV[cur ^ 1][tid * 8 + 2048]);
    }
    const unsigned short* K_ = lsK[cur];
    const unsigned short* V_ = lsV[cur];
    const bool dg = (kt == qt);
    const int kb = kt * 64;

    f32x4 st[4] = {};
    #pragma unroll
    for (int ks = 0; ks < 2; ++ks) {
      const int col = (((ks * 4 + g) ^ (lane & 7)) << 3);
      bf16x8 kf[4];
      #pragma unroll
      for (int mi = 0; mi < 4; ++mi)
        kf[mi] = *(const bf16x8*)&K_[(mi * 16 + c) * 64 + col];
      #pragma unroll
      for (int mi = 0; mi < 4; ++mi)
        st[mi] = __builtin_amdgcn_mfma_f32_16x16x32_bf16(kf[mi], qf[ks], st[mi], 0, 0, 0);
    }

    float mx = mr;
    #pragma unroll
    for (int mi = 0; mi < 4; ++mi)
      #pragma unroll
      for (int j = 0; j < 4; ++j) {
        float v = st[mi][j] * 0.125f;
        if (dg && (kb + mi * 16 + g * 4 + j) > qrow) v = -1e30f;
        st[mi][j] = v;
        mx = fmaxf(mx, v);
      }
    mx = fmaxf(mx, __shfl_xor(mx, 16));
    mx = fmaxf(mx, __shfl_xor(mx, 32));
    const float al = __expf(mr - mx);
    float sum = 0.0f;
    #pragma unroll
    for (int mi = 0; mi < 4; ++mi) {
      bf16x4 pk;
      #pragma unroll
      for (int j = 0; j < 4; ++j) {
        const float e = __expf(st[mi][j] - mx);
        sum += e;
        pk[j] = (short)f2b(e);
      }
      *(bf16x4*)&Pw[c * 64 + ((mi * 16 + g * 4) ^ ((c & 7) << 3))] = pk;
    }
    sum += __shfl_xor(sum, 16);
    sum += __shfl_xor(sum, 32);
    lr = lr * al + sum;
    mr = mx;

    float aj[4];
    #pragma unroll
    for (int j = 0; j < 4; ++j) aj[j] = __shfl(al, g * 4 + j);
    #pragma unroll
    for (int dj = 0; dj < 4; ++dj)
      #pragma unroll
      for (int j = 0; j < 4; ++j) accO[dj][j] *= aj[j];

    #pragma unroll
    for (int ks = 0; ks < 2; ++ks) {
      const int col = (((ks * 4 + g) ^ (c & 7)) << 3);
      const bf16x8 pa = *(const bf16x8*)&Pw[c * 64 + col];
      bf16x8 vf[4];
      #pragma unroll
      for (int dj = 0; dj < 4; ++dj)
        vf[dj] = *(const bf16x8*)&V_[(dj * 16 + c) * 64 + col];
      #pragma unroll
      for (int dj = 0; dj < 4; ++dj)
        accO[dj] = __builtin_amdgcn_mfma_f32_16x16x32_bf16(pa, vf[dj], accO[dj], 0, 0, 0);
    }
    __syncthreads();
  }

  const float linv = 1.0f / lr;
  float lj[4];
  #pragma unroll
  for (int j = 0; j < 4; ++j) lj[j] = __shfl(linv, g * 4 + j);
  unsigned short* obase = ob + (size_t)(b * 1024 + q0w) * 1024 + hh * 64;
  #pragma unroll
  for (int dj = 0; dj < 4; ++dj)
    #pragma unroll
    for (int j = 0; j < 4; ++j)
      obase[(size_t)(g * 4 + j) * 1024 + dj * 16 + c] = f2b(accO[dj][j] * lj[j]);
}

// ---------------- NT GEMM: C = A[M,K]*Bt[N,K]^T, bf16 in, f32 acc ----------------
template<int BM, int BN, bool BF16OUT, bool RELU, bool RESID, bool WVT = false, bool DBUF = false>
__global__ LB void gemm_nt(const unsigned short* __restrict__ A, const unsigned short* __restrict__ Bt,
                           void* __restrict__ Cv, const float* __restrict__ Res,
                           unsigned short* __restrict__ vTo,
                           int K, int lda, int ldb, int ldc) {
  constexpr int BK = 64;
  constexpr int WM = BM / 2, WN = BN / 2;
  constexpr int FM = WM / 16, FN = WN / 16;
  constexpr int PA = BM / 32, PB = BN / 32;
  constexpr int NB = DBUF ? 2 : 1;
  int f = blockIdx.x + gridDim.x * blockIdx.y;
  const int nwg = gridDim.x * gridDim.y;
  if ((nwg & 7) == 0) f = (f & 7) * (nwg >> 3) + (f >> 3);
  const int bx = f % gridDim.x, by = f / gridDim.x;

  const int tid = threadIdx.x;
  const int lane = tid & 63, wid = tid >> 6;
  const int wr = wid >> 1, wc = wid & 1;
  const int m0 = bx * BM, n0 = by * BN;

  __shared__ unsigned short lsA[NB][BM * BK];
  __shared__ unsigned short lsB[NB][BN * BK];

  f32x4 acc[FM][FN] = {};

  const int srow = tid >> 3;
  const int scol = ((tid & 7) ^ (srow & 7)) << 3;
  const unsigned short* gA = A + (size_t)(m0 + srow) * lda + scol;
  const unsigned short* gB = Bt + (size_t)(n0 + srow) * ldb + scol;

  const int fr = lane & 15;
  const int j7 = lane & 7;
  const int g4 = lane >> 4;

  if (DBUF) {
    #pragma unroll
    for (int p = 0; p < PA; ++p) GLDS(gA + (size_t)(p * 32) * lda, &lsA[0][tid * 8 + p * 2048]);
    #pragma unroll
    for (int p = 0; p < PB; ++p) GLDS(gB + (size_t)(p * 32) * ldb, &lsB[0][tid * 8 + p * 2048]);
    __syncthreads();
  }

  for (int k0 = 0; k0 < K; k0 += BK) {
    int cur = 0;
    if (DBUF) {
      cur = (k0 >> 6) & 1;
      if (k0 + BK < K) {
        #pragma unroll
        for (int p = 0; p < PA; ++p)
          GLDS(gA + (size_t)(p * 32) * lda + k0 + BK, &lsA[cur ^ 1][tid * 8 + p * 2048]);
        #pragma unroll
        for (int p = 0; p < PB; ++p)
          GLDS(gB + (size_t)(p * 32) * ldb + k0 + BK, &lsB[cur ^ 1][tid * 8 + p * 2048]);
      }
    } else {
      if (k0) __syncthreads();
      #pragma unroll
      for (int p = 0; p < PA; ++p)
        GLDS(gA + (size_t)(p * 32) * lda + k0, &lsA[0][tid * 8 + p * 2048]);
      #pragma unroll
      for (int p = 0; p < PB; ++p)
        GLDS(gB + (size_t)(p * 32) * ldb + k0, &lsB[0][tid * 8 + p * 2048]);
      __syncthreads();
    }

    const unsigned short* LA = lsA[cur];
    const unsigned short* LBp = lsB[cur];
    #pragma unroll
    for (int ks = 0; ks < 2; ++ks) {
      const int col = (((ks * 4 + g4) ^ j7) << 3);
      bf16x8 af[FM], bfv[FN];
      #pragma unroll
      for (int mi = 0; mi < FM; ++mi)
        af[mi] = *(const bf16x8*)&LA[(wr * WM + mi * 16 + fr) * BK + col];
      #pragma unroll
      for (int nj = 0; nj < FN; ++nj)
        bfv[nj] = *(const bf16x8*)&LBp[(wc * WN + nj * 16 + fr) * BK + col];
      #pragma unroll
      for (int mi = 0; mi < FM; ++mi)
        #pragma unroll
        for (int nj = 0; nj < FN; ++nj)
          acc[mi][nj] = __builtin_amdgcn_mfma_f32_16x16x32_bf16(af[mi], bfv[nj], acc[mi][nj], 0, 0, 0);
    }
    if (DBUF) __syncthreads();
  }

  const int r0 = (lane >> 4) * 4, c0 = lane & 15;
  #pragma unroll
  for (int mi = 0; mi < FM; ++mi) {
    #pragma unroll
    for (int nj = 0; nj < FN; ++nj) {
      const int c = n0 + wc * WN + nj * 16 + c0;
      const int rb = m0 + wr * WM + mi * 16 + r0;
      unsigned short us[4];
      #pragma unroll
      for (int j = 0; j < 4; ++j) {
        const int r = rb + j;
        float v = acc[mi][nj][j];
        if (RELU) v = fmaxf(v, 0.0f);
        if (RESID) v += Res[(size_t)r * ldc + c];
        const size_t o = (size_t)r * ldc + c;
        if (BF16OUT) { us[j] = f2b(v); ((unsigned short*)Cv)[o] = us[j]; }
        else ((float*)Cv)[o] = v;
      }
      if (WVT && c >= 1280) {
        const int bb = rb >> 10, t0 = rb & 1023;
        bf16x4 pk;
        #pragma unroll
        for (int j = 0; j < 4; ++j) pk[j] = (short)us[j];
        *(bf16x4*)&vTo[((size_t)(bb * 256 + (c - 1280))) * 1024 + t0] = pk;
      }
    }
  }
}

extern "C" void kernel_launch(void* const* d_in, const int* in_sizes, int n_in,
                              void* d_out, int out_size, void* d_ws, size_t ws_size,
                              hipStream_t stream) {
  (void)in_sizes; (void)n_in; (void)out_size;
  const int*   idx      = (const int*)d_in[0];
  const float* tok_emb  = (const float*)d_in[1];
  const float* pos_emb  = (const float*)d_in[2];
  const float* q_proj   = (const float*)d_in[3];
  const float* kv_proj  = (const float*)d_in[4];
  const float* out_proj = (const float*)d_in[5];
  const float* fc_in    = (const float*)d_in[6];
  const float* fc_out   = (const float*)d_in[7];
  const float* scale    = (const float*)d_in[8];
  const float* out_scl  = (const float*)d_in[9];
  const float* lm_head  = (const float*)d_in[10];
  float* out = (float*)d_out;

  char* ws = (char*)d_ws;
  size_t off = 0;
  auto alloc = [&](size_t bytes) -> void* {
    void* p = ws + off;
    off += (bytes + 255) & ~(size_t)255;
    return p;
  };
  unsigned short* WqkvT = (unsigned short*)alloc((size_t)2560 * 1024 * 2);
  unsigned short* WoT   = WqkvT + (size_t)1536 * 1024;
  unsigned short* F1T   = (unsigned short*)alloc((size_t)4096 * 1024 * 2);
  unsigned short* F2T   = (unsigned short*)alloc((size_t)1024 * 4096 * 2);
  float*  xbuf  = (float*)alloc((size_t)2048 * 1024 * 4);
  float*  hbuf  = (float*)alloc((size_t)2048 * 1024 * 4);
  float*  h2buf = (float*)alloc((size_t)2048 * 1024 * 4);
  unsigned short* actb  = (unsigned short*)alloc((size_t)2048 * 1024 * 2);
  unsigned short* qkvb  = (unsigned short*)alloc((size_t)2048 * 1536 * 2);
  unsigned short* vT    = (unsigned short*)alloc((size_t)2 * 256 * 1024 * 2);
  unsigned short* LmT   = (unsigned short*)alloc((size_t)32000 * 1024 * 2);
  unsigned short* ob    = (unsigned short*)alloc((size_t)2048 * 1024 * 2);
  unsigned short* m1    = (unsigned short*)alloc((size_t)2048 * 4096 * 2);
  if (off > ws_size) return;

  const dim3 thr(256);

  embed_kernel<<<dim3(2048), thr, 0, stream>>>(idx, tok_emb, pos_emb, xbuf);

  for (int l = 0; l < 8; ++l) {
    const float* qp  = q_proj + (size_t)l * 1024 * 1024;
    const float* op  = out_proj + (size_t)l * 1024 * 1024;
    const float* kvp = kv_proj + (size_t)l * 2 * 1024 * 256;
    const float* w1 = scale + (size_t)l * 2048;
    const float* w2 = w1 + 1024;

    // merged: ln1 + all weight transposes (independent work, one launch)
    tr_ln<<<dim3(12800), thr, 0, stream>>>(
        qp, op, kvp, WqkvT,
        fc_in + (size_t)l * 1024 * 4096, fc_out + (size_t)l * 4096 * 1024, F1T, F2T,
        xbuf, w1, hbuf, actb);
    // qkv = h @ Wqkv (V columns also written transposed into vT), dbuf
    gemm_nt<128, 64, true, false, false, true, true><<<dim3(16, 24), thr, 0, stream>>>(
        actb, WqkvT, qkvb, nullptr, vT, 1024, 1024, 1024, 1536);
    attn_fused<<<dim3(16, 32), thr, 0, stream>>>(qkvb, vT, ob);
    // x = h + o @ Wo, dbuf
    gemm_nt<128, 64, false, false, true, false, true><<<dim3(16, 16), thr, 0, stream>>>(
        ob, WoT, xbuf, hbuf, nullptr, 1024, 1024, 1024, 1024);
    ln_kernel<true><<<dim3(2048), thr, 0, stream>>>(xbuf, w2, h2buf, actb);
    // m1 = relu(h2 @ fc1), dbuf
    gemm_nt<128, 128, true, true, false, false, true><<<dim3(16, 32), thr, 0, stream>>>(
        actb, F1T, m1, nullptr, nullptr, 1024, 1024, 1024, 4096);
    // x = h2 + m1 @ fc2, dbuf
    gemm_nt<128, 64, false, false, true, false, true><<<dim3(16, 16), thr, 0, stream>>>(
        m1, F2T, xbuf, h2buf, nullptr, 4096, 4096, 4096, 1024);
  }

  // merged tail: final ln + lm_head transpose (independent, one launch)
  tr_ln_tail<<<dim3(34048), thr, 0, stream>>>(lm_head, LmT, xbuf, out_scl, actb);
  // logits: 128^2 gemm_nt (measured floor for this structure)
  gemm_nt<128, 128, false, false, false><<<dim3(16, 250), thr, 0, stream>>>(
      actb, LmT, out, nullptr, nullptr, 1024, 1024, 1024, 32000);
}